// Round 1
// baseline (3205.740 us; speedup 1.0000x reference)
//
#include <hip/hip_runtime.h>
#include <math.h>

#define NN 50000
#define NE 800000
#define HD 64
#define ECH 32
#define NHEAD 4

__device__ __forceinline__ float ssp_f(float v) {
    // shifted softplus: log(1+e^v) - log(2), numerically stable
    return fmaxf(v, 0.0f) + log1pf(__expf(-fabsf(v))) - 0.69314718055994531f;
}

// ---------------- Kernel A: per-node grouped q/k/v linears ----------------
__global__ __launch_bounds__(256) void node_transform_kernel(
    const float* __restrict__ x,
    const float* __restrict__ k_w, const float* __restrict__ q_w, const float* __restrict__ v_w,
    float* __restrict__ hq, float* __restrict__ hk, float* __restrict__ hv)
{
    __shared__ float skw[NHEAD * 256], sqw[NHEAD * 256], svw[NHEAD * 256];
    for (int i = threadIdx.x; i < NHEAD * 256; i += 256) {
        skw[i] = k_w[i]; sqw[i] = q_w[i]; svw[i] = v_w[i];
    }
    __syncthreads();
    int n = blockIdx.x * 256 + threadIdx.x;
    if (n >= NN) return;
    const float* xn = x + (size_t)n * HD;
    for (int h = 0; h < NHEAD; ++h) {
        float xr[16];
        {
            const float4* xp = (const float4*)(xn + h * 16);
            #pragma unroll
            for (int j = 0; j < 4; ++j) *(float4*)&xr[4 * j] = xp[j];
        }
        float rq[16], rk[16], rv[16];
        for (int o = 0; o < 16; ++o) {
            const float* wq = sqw + h * 256 + o * 16;
            const float* wk = skw + h * 256 + o * 16;
            const float* wv = svw + h * 256 + o * 16;
            float sq = 0.f, sk = 0.f, sv = 0.f;
            #pragma unroll
            for (int i = 0; i < 16; ++i) {
                sq += xr[i] * wq[i];
                sk += xr[i] * wk[i];
                sv += xr[i] * wv[i];
            }
            rq[o] = sq; rk[o] = sk; rv[o] = sv;
        }
        float4* oq = (float4*)(hq + (size_t)n * HD + h * 16);
        float4* ok = (float4*)(hk + (size_t)n * HD + h * 16);
        float4* ov = (float4*)(hv + (size_t)n * HD + h * 16);
        #pragma unroll
        for (int j = 0; j < 4; ++j) {
            oq[j] = *(float4*)&rq[4 * j];
            ok[j] = *(float4*)&rk[4 * j];
            ov[j] = *(float4*)&rv[4 * j];
        }
    }
}

// ---------------- Kernel B: per-edge fused attention + atomic aggregation ----------------
__global__ __launch_bounds__(256) void edge_kernel(
    const int* __restrict__ ei,
    const float* __restrict__ ea,
    const float* __restrict__ wkn_w1, const float* __restrict__ wkn_b1,
    const float* __restrict__ wkn_w2, const float* __restrict__ wkn_b2,
    const float* __restrict__ wkl_w,  const float* __restrict__ wkl_b,
    const float* __restrict__ wvn_w1, const float* __restrict__ wvn_b1,
    const float* __restrict__ wvn_w2, const float* __restrict__ wvn_b2,
    const float* __restrict__ wvl_w,  const float* __restrict__ wvl_b,
    const float* __restrict__ hq, const float* __restrict__ hk, const float* __restrict__ hv,
    float* __restrict__ numer, float* __restrict__ denom)
{
    __shared__ float s_kn1[512], s_vn1[512];
    __shared__ float s_kn2[256], s_vn2[256], s_kl[256], s_vl[256];
    __shared__ float s_knb1[16], s_knb2[16], s_klb[16];
    __shared__ float s_vnb1[16], s_vnb2[16], s_vlb[16];
    for (int i = threadIdx.x; i < 512; i += 256) { s_kn1[i] = wkn_w1[i]; s_vn1[i] = wvn_w1[i]; }
    {
        int i = threadIdx.x;
        if (i < 256) { s_kn2[i] = wkn_w2[i]; s_vn2[i] = wvn_w2[i]; s_kl[i] = wkl_w[i]; s_vl[i] = wvl_w[i]; }
        if (i < 16) {
            s_knb1[i] = wkn_b1[i]; s_knb2[i] = wkn_b2[i]; s_klb[i] = wkl_b[i];
            s_vnb1[i] = wvn_b1[i]; s_vnb2[i] = wvn_b2[i]; s_vlb[i] = wvl_b[i];
        }
    }
    __syncthreads();
    int e = blockIdx.x * 256 + threadIdx.x;
    if (e >= NE) return;

    int row = ei[e];
    int col = ei[NE + e];

    float eav[32];
    {
        const float4* p = (const float4*)(ea + (size_t)e * ECH);
        #pragma unroll
        for (int i = 0; i < 8; ++i) *(float4*)&eav[4 * i] = p[i];
    }

    // edge MLPs: layer1(32->16) + ssp, layer2(16->16), for both K-net and V-net
    float h1k[16], h1v[16];
    for (int o = 0; o < 16; ++o) {
        float sk = s_knb1[o], sv = s_vnb1[o];
        #pragma unroll
        for (int i = 0; i < 32; ++i) {
            sk += eav[i] * s_kn1[o * 32 + i];
            sv += eav[i] * s_vn1[o * 32 + i];
        }
        h1k[o] = ssp_f(sk);
        h1v[o] = ssp_f(sv);
    }
    float Wk[16], Wv[16];
    for (int o = 0; o < 16; ++o) {
        float sk = s_knb2[o], sv = s_vnb2[o];
        #pragma unroll
        for (int i = 0; i < 16; ++i) {
            sk += h1k[i] * s_kn2[o * 16 + i];
            sv += h1v[i] * s_vn2[o * 16 + i];
        }
        Wk[o] = sk; Wv[o] = sv;
    }

    const float* qbase = hq + (size_t)row * HD;
    const float* kbase = hk + (size_t)col * HD;
    const float* vbase = hv + (size_t)col * HD;
    float* nbase = numer + (size_t)row * HD;

    for (int h = 0; h < NHEAD; ++h) {
        float qr[16], tk[16];
        {
            const float4* qp = (const float4*)(qbase + h * 16);
            const float4* kp = (const float4*)(kbase + h * 16);
            float kc[16];
            #pragma unroll
            for (int j = 0; j < 4; ++j) *(float4*)&qr[4 * j] = qp[j];
            #pragma unroll
            for (int j = 0; j < 4; ++j) *(float4*)&kc[4 * j] = kp[j];
            #pragma unroll
            for (int i = 0; i < 16; ++i) tk[i] = Wk[i] * kc[i];
        }
        // qk = q . (wkl @ (Wk*k) + b)
        float qk = 0.f;
        for (int o = 0; o < 16; ++o) {
            float s = s_klb[o];
            #pragma unroll
            for (int i = 0; i < 16; ++i) s += tk[i] * s_kl[o * 16 + i];
            qk += qr[o] * s;
        }
        // softmax shift-invariance: accumulate unnormalized exp weights
        float w = __expf(qk);

        float tv[16];
        {
            const float4* vp = (const float4*)(vbase + h * 16);
            float vc[16];
            #pragma unroll
            for (int j = 0; j < 4; ++j) *(float4*)&vc[4 * j] = vp[j];
            #pragma unroll
            for (int i = 0; i < 16; ++i) tv[i] = Wv[i] * vc[i];
        }
        for (int o = 0; o < 16; ++o) {
            float s = s_vlb[o];
            #pragma unroll
            for (int i = 0; i < 16; ++i) s += tv[i] * s_vl[o * 16 + i];
            atomicAdd(nbase + h * 16 + o, w * s);
        }
        atomicAdd(denom + (size_t)row * NHEAD + h, w);
    }
}

// ---------------- Kernel C: finalize (cen linear + normalize + ssp + out linear) ----------------
__global__ __launch_bounds__(256) void finalize_kernel(
    const float* __restrict__ x,
    const float* __restrict__ numer, const float* __restrict__ denom,
    const float* __restrict__ cen_w, const float* __restrict__ cen_b,
    const float* __restrict__ out_w, const float* __restrict__ out_b,
    float* __restrict__ out)
{
    // weights stored TRANSPOSED in LDS: s[i*64+o] = w[o*64+i]
    // -> lane c reads s[i*64+c]: banks c%32, 2-way aliasing = free
    __shared__ float s_cw[4096], s_ow[4096];
    __shared__ float s_x[4][64], s_t[4][64];
    for (int idx = threadIdx.x; idx < 4096; idx += 256) {
        int o = idx & 63, i = idx >> 6;
        s_cw[i * 64 + o] = cen_w[o * 64 + i];
        s_ow[i * 64 + o] = out_w[o * 64 + i];
    }
    int local = threadIdx.x >> 6;   // node within block, uniform per wave
    int c = threadIdx.x & 63;       // channel = lane
    int n = blockIdx.x * 4 + local;
    bool valid = n < NN;
    s_x[local][c] = valid ? x[(size_t)n * HD + c] : 0.f;
    __syncthreads();
    if (valid) {
        float s = cen_b[c];
        #pragma unroll 8
        for (int i = 0; i < 64; ++i) s += s_x[local][i] * s_cw[i * 64 + c];
        float d = denom[(size_t)n * NHEAD + (c >> 4)];
        float num = numer[(size_t)n * HD + c];
        s += (d > 0.f) ? (num / d) : 0.f;
        s_t[local][c] = ssp_f(s);
    }
    __syncthreads();
    if (valid) {
        float s = out_b[c];
        #pragma unroll 8
        for (int i = 0; i < 64; ++i) s += s_t[local][i] * s_ow[i * 64 + c];
        out[(size_t)n * HD + c] = s;
    }
}

extern "C" void kernel_launch(void* const* d_in, const int* in_sizes, int n_in,
                              void* d_out, int out_size, void* d_ws, size_t ws_size,
                              hipStream_t stream)
{
    const float* x      = (const float*)d_in[0];
    const int*   ei     = (const int*)d_in[1];
    const float* ea     = (const float*)d_in[2];
    const float* k_w    = (const float*)d_in[3];
    const float* q_w    = (const float*)d_in[4];
    const float* v_w    = (const float*)d_in[5];
    const float* wkn_w1 = (const float*)d_in[6];
    const float* wkn_b1 = (const float*)d_in[7];
    const float* wkn_w2 = (const float*)d_in[8];
    const float* wkn_b2 = (const float*)d_in[9];
    const float* wkl_w  = (const float*)d_in[10];
    const float* wkl_b  = (const float*)d_in[11];
    const float* wvn_w1 = (const float*)d_in[12];
    const float* wvn_b1 = (const float*)d_in[13];
    const float* wvn_w2 = (const float*)d_in[14];
    const float* wvn_b2 = (const float*)d_in[15];
    const float* wvl_w  = (const float*)d_in[16];
    const float* wvl_b  = (const float*)d_in[17];
    const float* cen_w  = (const float*)d_in[18];
    const float* cen_b  = (const float*)d_in[19];
    const float* out_w  = (const float*)d_in[20];
    const float* out_b  = (const float*)d_in[21];
    float* out = (float*)d_out;

    float* hq    = (float*)d_ws;                  // N*64
    float* hk    = hq + (size_t)NN * HD;          // N*64
    float* hv    = hk + (size_t)NN * HD;          // N*64
    float* numer = hv + (size_t)NN * HD;          // N*64
    float* denom = numer + (size_t)NN * HD;       // N*4

    hipMemsetAsync(numer, 0, ((size_t)NN * HD + (size_t)NN * NHEAD) * sizeof(float), stream);
    node_transform_kernel<<<(NN + 255) / 256, 256, 0, stream>>>(x, k_w, q_w, v_w, hq, hk, hv);
    edge_kernel<<<(NE + 255) / 256, 256, 0, stream>>>(
        ei, ea, wkn_w1, wkn_b1, wkn_w2, wkn_b2, wkl_w, wkl_b,
        wvn_w1, wvn_b1, wvn_w2, wvn_b2, wvl_w, wvl_b,
        hq, hk, hv, numer, denom);
    finalize_kernel<<<(NN + 3) / 4, 256, 0, stream>>>(
        x, numer, denom, cen_w, cen_b, out_w, out_b, out);
}

// Round 2
// 924.777 us; speedup vs baseline: 3.4665x; 3.4665x over previous
//
#include <hip/hip_runtime.h>
#include <math.h>
#include <stdint.h>

#define NN 50000
#define NE 800000
#define HD 64
#define ECH 32
#define NHEAD 4

__device__ __forceinline__ float ssp_f(float v) {
    // shifted softplus: log(1+e^v) - log(2), numerically stable
    return fmaxf(v, 0.0f) + log1pf(__expf(-fabsf(v))) - 0.69314718055994531f;
}

__device__ __forceinline__ uint32_t f2bf_bits(float f) {
    // fp32 -> bf16 bits, round-to-nearest-even (finite inputs only)
    uint32_t u = __float_as_uint(f);
    return (u + 0x7FFFu + ((u >> 16) & 1u)) >> 16;
}

__device__ __forceinline__ float bf2f(uint32_t b) {
    return __uint_as_float(b << 16);
}

// ---------------- Kernel A: per-node q/k/v + fold wkl into q side ----------------
// qt = wkl^T @ q   (so qk = qt . (Wk*k) + qb),  qb = q . klb
__global__ __launch_bounds__(256) void node_transform_kernel(
    const float* __restrict__ x,
    const float* __restrict__ k_w, const float* __restrict__ q_w, const float* __restrict__ v_w,
    const float* __restrict__ wkl_w, const float* __restrict__ wkl_b,
    float* __restrict__ qt, float* __restrict__ qb,
    float* __restrict__ hk, float* __restrict__ hv)
{
    __shared__ float skw[NHEAD * 256], sqw[NHEAD * 256], svw[NHEAD * 256];
    __shared__ float s_kl[256], s_klb[16];
    for (int i = threadIdx.x; i < NHEAD * 256; i += 256) {
        skw[i] = k_w[i]; sqw[i] = q_w[i]; svw[i] = v_w[i];
    }
    if (threadIdx.x < 256) s_kl[threadIdx.x] = wkl_w[threadIdx.x];
    if (threadIdx.x < 16) s_klb[threadIdx.x] = wkl_b[threadIdx.x];
    __syncthreads();
    int n = blockIdx.x * 256 + threadIdx.x;
    if (n >= NN) return;
    const float* xn = x + (size_t)n * HD;
    float qbv[NHEAD];
    for (int h = 0; h < NHEAD; ++h) {
        float xr[16];
        {
            const float4* xp = (const float4*)(xn + h * 16);
            #pragma unroll
            for (int j = 0; j < 4; ++j) *(float4*)&xr[4 * j] = xp[j];
        }
        float rq[16], rk[16], rv[16];
        for (int o = 0; o < 16; ++o) {
            const float* wq = sqw + h * 256 + o * 16;
            const float* wk = skw + h * 256 + o * 16;
            const float* wv = svw + h * 256 + o * 16;
            float sq = 0.f, sk = 0.f, sv = 0.f;
            #pragma unroll
            for (int i = 0; i < 16; ++i) {
                sq += xr[i] * wq[i];
                sk += xr[i] * wk[i];
                sv += xr[i] * wv[i];
            }
            rq[o] = sq; rk[o] = sk; rv[o] = sv;
        }
        // qt_i = sum_o q_o * wkl[o][i];  qb = sum_o q_o * klb[o]
        float rqt[16];
        float qbh = 0.f;
        for (int i = 0; i < 16; ++i) {
            float s = 0.f;
            #pragma unroll
            for (int o = 0; o < 16; ++o) s += rq[o] * s_kl[o * 16 + i];
            rqt[i] = s;
        }
        #pragma unroll
        for (int o = 0; o < 16; ++o) qbh += rq[o] * s_klb[o];
        qbv[h] = qbh;

        float4* oq = (float4*)(qt + (size_t)n * HD + h * 16);
        float4* ok = (float4*)(hk + (size_t)n * HD + h * 16);
        float4* ov = (float4*)(hv + (size_t)n * HD + h * 16);
        #pragma unroll
        for (int j = 0; j < 4; ++j) {
            oq[j] = *(float4*)&rqt[4 * j];
            ok[j] = *(float4*)&rk[4 * j];
            ov[j] = *(float4*)&rv[4 * j];
        }
    }
    *(float4*)(qb + (size_t)n * NHEAD) = *(float4*)&qbv[0];
}

// ---------------- Kernel B: per-edge compute (no scatter atomics) ----------------
// payload[e][c] = bf16( w_h * Wv_i * v_col[c] ),  wfac[e][h] = w_h,  counts[row]++
__global__ __launch_bounds__(256) void edge_compute_kernel(
    const int* __restrict__ ei,
    const float* __restrict__ ea,
    const float* __restrict__ wkn_w1, const float* __restrict__ wkn_b1,
    const float* __restrict__ wkn_w2, const float* __restrict__ wkn_b2,
    const float* __restrict__ wvn_w1, const float* __restrict__ wvn_b1,
    const float* __restrict__ wvn_w2, const float* __restrict__ wvn_b2,
    const float* __restrict__ qt, const float* __restrict__ qb,
    const float* __restrict__ hk, const float* __restrict__ hv,
    uint16_t* __restrict__ payload, float* __restrict__ wfac, int* __restrict__ counts)
{
    __shared__ float s_kn1[512], s_vn1[512];
    __shared__ float s_kn2[256], s_vn2[256];
    __shared__ float s_knb1[16], s_knb2[16], s_vnb1[16], s_vnb2[16];
    for (int i = threadIdx.x; i < 512; i += 256) { s_kn1[i] = wkn_w1[i]; s_vn1[i] = wvn_w1[i]; }
    if (threadIdx.x < 256) { s_kn2[threadIdx.x] = wkn_w2[threadIdx.x]; s_vn2[threadIdx.x] = wvn_w2[threadIdx.x]; }
    if (threadIdx.x < 16) {
        s_knb1[threadIdx.x] = wkn_b1[threadIdx.x]; s_knb2[threadIdx.x] = wkn_b2[threadIdx.x];
        s_vnb1[threadIdx.x] = wvn_b1[threadIdx.x]; s_vnb2[threadIdx.x] = wvn_b2[threadIdx.x];
    }
    __syncthreads();
    int e = blockIdx.x * 256 + threadIdx.x;
    if (e >= NE) return;

    int row = ei[e];
    int col = ei[NE + e];

    float eav[32];
    {
        const float4* p = (const float4*)(ea + (size_t)e * ECH);
        #pragma unroll
        for (int i = 0; i < 8; ++i) *(float4*)&eav[4 * i] = p[i];
    }
    float4 qbv = *(const float4*)(qb + (size_t)row * NHEAD);

    // edge MLPs (both nets interleaved for ILP)
    float h1k[16], h1v[16];
    for (int o = 0; o < 16; ++o) {
        float sk = s_knb1[o], sv = s_vnb1[o];
        #pragma unroll
        for (int i = 0; i < 32; ++i) {
            sk += eav[i] * s_kn1[o * 32 + i];
            sv += eav[i] * s_vn1[o * 32 + i];
        }
        h1k[o] = ssp_f(sk);
        h1v[o] = ssp_f(sv);
    }
    float Wk[16], Wv[16];
    for (int o = 0; o < 16; ++o) {
        float sk = s_knb2[o], sv = s_vnb2[o];
        #pragma unroll
        for (int i = 0; i < 16; ++i) {
            sk += h1k[i] * s_kn2[o * 16 + i];
            sv += h1v[i] * s_vn2[o * 16 + i];
        }
        Wk[o] = sk; Wv[o] = sv;
    }

    const float* qtb = qt + (size_t)row * HD;
    const float* kbase = hk + (size_t)col * HD;
    const float* vbase = hv + (size_t)col * HD;

    uint32_t pk[32];      // 64 bf16 packed
    float wf[NHEAD];
    const float qbarr[4] = {qbv.x, qbv.y, qbv.z, qbv.w};
    for (int h = 0; h < NHEAD; ++h) {
        float qr[16], kc[16], vc[16];
        {
            const float4* qp = (const float4*)(qtb + h * 16);
            const float4* kp = (const float4*)(kbase + h * 16);
            const float4* vp = (const float4*)(vbase + h * 16);
            #pragma unroll
            for (int j = 0; j < 4; ++j) *(float4*)&qr[4 * j] = qp[j];
            #pragma unroll
            for (int j = 0; j < 4; ++j) *(float4*)&kc[4 * j] = kp[j];
            #pragma unroll
            for (int j = 0; j < 4; ++j) *(float4*)&vc[4 * j] = vp[j];
        }
        float qk = qbarr[h];
        #pragma unroll
        for (int i = 0; i < 16; ++i) qk += qr[i] * Wk[i] * kc[i];
        float w = __expf(qk);   // softmax shift-invariance: no max subtraction needed
        wf[h] = w;
        #pragma unroll
        for (int i = 0; i < 16; i += 2) {
            uint32_t lo = f2bf_bits(w * Wv[i] * vc[i]);
            uint32_t hi = f2bf_bits(w * Wv[i + 1] * vc[i + 1]);
            pk[h * 8 + i / 2] = lo | (hi << 16);
        }
    }
    // coalesced-per-lane 128B payload write (8 x 16B)
    uint4* pd = (uint4*)(payload + (size_t)e * HD);
    #pragma unroll
    for (int j = 0; j < 8; ++j) pd[j] = *(uint4*)&pk[4 * j];
    *(float4*)(wfac + (size_t)e * NHEAD) = *(float4*)&wf[0];

    atomicAdd(counts + row, 1);
}

// ---------------- Kernel C: exclusive scan over counts -> offsets, cursor ----------------
__global__ __launch_bounds__(1024) void scan_kernel(
    const int* __restrict__ counts, int* __restrict__ offsets, int* __restrict__ cursor)
{
    __shared__ int tmp[1024];
    __shared__ int s_carry;
    if (threadIdx.x == 0) s_carry = 0;
    __syncthreads();
    for (int base = 0; base < NN; base += 1024) {
        int i = base + (int)threadIdx.x;
        int v = (i < NN) ? counts[i] : 0;
        tmp[threadIdx.x] = v;
        __syncthreads();
        #pragma unroll
        for (int d = 1; d < 1024; d <<= 1) {
            int t = (threadIdx.x >= (unsigned)d) ? tmp[threadIdx.x - d] : 0;
            __syncthreads();
            tmp[threadIdx.x] += t;
            __syncthreads();
        }
        int incl = tmp[threadIdx.x];
        int carry = s_carry;
        if (i < NN) { int excl = carry + incl - v; offsets[i] = excl; cursor[i] = excl; }
        __syncthreads();
        if (threadIdx.x == 1023) s_carry = carry + tmp[1023];
        __syncthreads();
    }
}

// ---------------- Kernel D: scatter edge ids into CSR lists ----------------
__global__ __launch_bounds__(256) void scatter_kernel(
    const int* __restrict__ ei, int* __restrict__ cursor, int* __restrict__ elist)
{
    int e = blockIdx.x * 256 + threadIdx.x;
    if (e >= NE) return;
    int r = ei[e];
    int pos = atomicAdd(cursor + r, 1);
    elist[pos] = e;
}

// ---------------- Kernel E: gather + normalize + wvl + cen + ssp + out ----------------
__global__ __launch_bounds__(256) void gather_finalize_kernel(
    const float* __restrict__ x,
    const uint16_t* __restrict__ payload, const float* __restrict__ wfac,
    const int* __restrict__ offsets, const int* __restrict__ counts,
    const int* __restrict__ elist,
    const float* __restrict__ wvl_w, const float* __restrict__ wvl_b,
    const float* __restrict__ cen_w, const float* __restrict__ cen_b,
    const float* __restrict__ out_w, const float* __restrict__ out_b,
    float* __restrict__ out)
{
    // cen/out weights TRANSPOSED in LDS: lane c reads s[i*64+c] -> 2-way bank alias = free
    __shared__ float s_cw[4096], s_ow[4096];
    __shared__ float s_wvl[256], s_vlb[16];
    __shared__ float s_m[4][64], s_x[4][64], s_t[4][64];
    for (int idx = threadIdx.x; idx < 4096; idx += 256) {
        int o = idx & 63, i = idx >> 6;
        s_cw[i * 64 + o] = cen_w[o * 64 + i];
        s_ow[i * 64 + o] = out_w[o * 64 + i];
    }
    if (threadIdx.x < 256) s_wvl[threadIdx.x] = wvl_w[threadIdx.x];
    if (threadIdx.x < 16) s_vlb[threadIdx.x] = wvl_b[threadIdx.x];

    int l = threadIdx.x >> 6;    // node slot within block (wave-uniform)
    int c = threadIdx.x & 63;    // channel = lane
    int h = c >> 4;
    int n = blockIdx.x * 4 + l;
    bool valid = n < NN;

    float u = 0.f, ds = 0.f;
    int deg = 0;
    if (valid) {
        int st = offsets[n];
        deg = counts[n];
        for (int i = 0; i < deg; ++i) {
            int e = elist[st + i];
            u += bf2f((uint32_t)payload[(size_t)e * HD + c]);   // coalesced 128B per edge
            ds += wfac[(size_t)e * NHEAD + h];                  // broadcast within head group
        }
    }
    float m = (deg > 0) ? (u / ds) : 0.f;
    s_m[l][c] = m;
    s_x[l][c] = valid ? x[(size_t)n * HD + c] : 0.f;
    __syncthreads();

    float aggr = 0.f;
    if (deg > 0) {
        int o = c & 15;
        float s = s_vlb[o];
        #pragma unroll
        for (int i = 0; i < 16; ++i) s += s_m[l][h * 16 + i] * s_wvl[o * 16 + i];
        aggr = s;
    }
    float sc = cen_b[c];
    #pragma unroll 8
    for (int i = 0; i < 64; ++i) sc += s_x[l][i] * s_cw[i * 64 + c];
    sc += aggr;
    s_t[l][c] = ssp_f(sc);
    __syncthreads();

    if (valid) {
        float s = out_b[c];
        #pragma unroll 8
        for (int i = 0; i < 64; ++i) s += s_t[l][i] * s_ow[i * 64 + c];
        out[(size_t)n * HD + c] = s;
    }
}

extern "C" void kernel_launch(void* const* d_in, const int* in_sizes, int n_in,
                              void* d_out, int out_size, void* d_ws, size_t ws_size,
                              hipStream_t stream)
{
    const float* x      = (const float*)d_in[0];
    const int*   ei     = (const int*)d_in[1];
    const float* ea     = (const float*)d_in[2];
    const float* k_w    = (const float*)d_in[3];
    const float* q_w    = (const float*)d_in[4];
    const float* v_w    = (const float*)d_in[5];
    const float* wkn_w1 = (const float*)d_in[6];
    const float* wkn_b1 = (const float*)d_in[7];
    const float* wkn_w2 = (const float*)d_in[8];
    const float* wkn_b2 = (const float*)d_in[9];
    const float* wkl_w  = (const float*)d_in[10];
    const float* wkl_b  = (const float*)d_in[11];
    const float* wvn_w1 = (const float*)d_in[12];
    const float* wvn_b1 = (const float*)d_in[13];
    const float* wvn_w2 = (const float*)d_in[14];
    const float* wvn_b2 = (const float*)d_in[15];
    const float* wvl_w  = (const float*)d_in[16];
    const float* wvl_b  = (const float*)d_in[17];
    const float* cen_w  = (const float*)d_in[18];
    const float* cen_b  = (const float*)d_in[19];
    const float* out_w  = (const float*)d_in[20];
    const float* out_b  = (const float*)d_in[21];
    float* out = (float*)d_out;

    // workspace layout (float-aligned large arrays first, then bf16 payload, then ints)
    float* qt    = (float*)d_ws;                          // NN*64
    float* hk    = qt + (size_t)NN * HD;                  // NN*64
    float* hv    = hk + (size_t)NN * HD;                  // NN*64
    float* qb    = hv + (size_t)NN * HD;                  // NN*4
    float* wfac  = qb + (size_t)NN * NHEAD;               // NE*4
    uint16_t* payload = (uint16_t*)(wfac + (size_t)NE * NHEAD);   // NE*64 bf16
    int* counts  = (int*)(payload + (size_t)NE * HD);     // NN
    int* offsets = counts + NN;                           // NN
    int* cursor  = offsets + NN;                          // NN
    int* elist   = cursor + NN;                           // NE

    hipMemsetAsync(counts, 0, (size_t)NN * sizeof(int), stream);
    node_transform_kernel<<<(NN + 255) / 256, 256, 0, stream>>>(
        x, k_w, q_w, v_w, wkl_w, wkl_b, qt, qb, hk, hv);
    edge_compute_kernel<<<(NE + 255) / 256, 256, 0, stream>>>(
        ei, ea, wkn_w1, wkn_b1, wkn_w2, wkn_b2,
        wvn_w1, wvn_b1, wvn_w2, wvn_b2,
        qt, qb, hk, hv, payload, wfac, counts);
    scan_kernel<<<1, 1024, 0, stream>>>(counts, offsets, cursor);
    scatter_kernel<<<(NE + 255) / 256, 256, 0, stream>>>(ei, cursor, elist);
    gather_finalize_kernel<<<(NN + 3) / 4, 256, 0, stream>>>(
        x, payload, wfac, offsets, counts, elist,
        wvl_w, wvl_b, cen_w, cen_b, out_w, out_b, out);
}

// Round 3
// 556.217 us; speedup vs baseline: 5.7635x; 1.6626x over previous
//
#include <hip/hip_runtime.h>
#include <math.h>
#include <stdint.h>

#define NN 50000
#define NE 800000
#define HD 64
#define ECH 32
#define NHEAD 4
#define NBLK 196   // ceil(NN/256)

__device__ __forceinline__ float ssp_f(float v) {
    return fmaxf(v, 0.0f) + log1pf(__expf(-fabsf(v))) - 0.69314718055994531f;
}

__device__ __forceinline__ uint32_t f2bf_bits(float f) {
    uint32_t u = __float_as_uint(f);
    return (u + 0x7FFFu + ((u >> 16) & 1u)) >> 16;
}
__device__ __forceinline__ float bf2f(uint32_t b) { return __uint_as_float(b << 16); }

__device__ __forceinline__ void unpack8(uint4 p, float* o) {
    o[0] = bf2f(p.x & 0xffffu); o[1] = bf2f(p.x >> 16);
    o[2] = bf2f(p.y & 0xffffu); o[3] = bf2f(p.y >> 16);
    o[4] = bf2f(p.z & 0xffffu); o[5] = bf2f(p.z >> 16);
    o[6] = bf2f(p.w & 0xffffu); o[7] = bf2f(p.w >> 16);
}
__device__ __forceinline__ uint4 pack8(const float* s) {
    uint4 r;
    r.x = f2bf_bits(s[0]) | (f2bf_bits(s[1]) << 16);
    r.y = f2bf_bits(s[2]) | (f2bf_bits(s[3]) << 16);
    r.z = f2bf_bits(s[4]) | (f2bf_bits(s[5]) << 16);
    r.w = f2bf_bits(s[6]) | (f2bf_bits(s[7]) << 16);
    return r;
}

// ---------------- Kernel A: node q/k/v, fold wkl into q side, bf16 outputs ----------------
__global__ __launch_bounds__(256) void node_transform_kernel(
    const float* __restrict__ x,
    const float* __restrict__ k_w, const float* __restrict__ q_w, const float* __restrict__ v_w,
    const float* __restrict__ wkl_w, const float* __restrict__ wkl_b,
    uint16_t* __restrict__ qt, float* __restrict__ qb,
    uint16_t* __restrict__ hk, uint16_t* __restrict__ hv)
{
    __shared__ float skw[NHEAD * 256], sqw[NHEAD * 256], svw[NHEAD * 256];
    __shared__ float s_kl[256], s_klb[16];
    for (int i = threadIdx.x; i < NHEAD * 256; i += 256) {
        skw[i] = k_w[i]; sqw[i] = q_w[i]; svw[i] = v_w[i];
    }
    if (threadIdx.x < 256) s_kl[threadIdx.x] = wkl_w[threadIdx.x];
    if (threadIdx.x < 16) s_klb[threadIdx.x] = wkl_b[threadIdx.x];
    __syncthreads();
    int n = blockIdx.x * 256 + threadIdx.x;
    if (n >= NN) return;
    const float* xn = x + (size_t)n * HD;
    float qbv[NHEAD];
    for (int h = 0; h < NHEAD; ++h) {
        float xr[16];
        {
            const float4* xp = (const float4*)(xn + h * 16);
            #pragma unroll
            for (int j = 0; j < 4; ++j) *(float4*)&xr[4 * j] = xp[j];
        }
        float rq[16], rk[16], rv[16];
        for (int o = 0; o < 16; ++o) {
            const float* wq = sqw + h * 256 + o * 16;
            const float* wk = skw + h * 256 + o * 16;
            const float* wv = svw + h * 256 + o * 16;
            float sq = 0.f, sk = 0.f, sv = 0.f;
            #pragma unroll
            for (int i = 0; i < 16; ++i) {
                sq += xr[i] * wq[i];
                sk += xr[i] * wk[i];
                sv += xr[i] * wv[i];
            }
            rq[o] = sq; rk[o] = sk; rv[o] = sv;
        }
        float rqt[16];
        float qbh = 0.f;
        for (int i = 0; i < 16; ++i) {
            float s = 0.f;
            #pragma unroll
            for (int o = 0; o < 16; ++o) s += rq[o] * s_kl[o * 16 + i];
            rqt[i] = s;
        }
        #pragma unroll
        for (int o = 0; o < 16; ++o) qbh += rq[o] * s_klb[o];
        qbv[h] = qbh;

        uint4* oq = (uint4*)(qt + (size_t)n * HD + h * 16);
        uint4* ok = (uint4*)(hk + (size_t)n * HD + h * 16);
        uint4* ov = (uint4*)(hv + (size_t)n * HD + h * 16);
        oq[0] = pack8(rqt); oq[1] = pack8(rqt + 8);
        ok[0] = pack8(rk);  ok[1] = pack8(rk + 8);
        ov[0] = pack8(rv);  ov[1] = pack8(rv + 8);
    }
    *(float4*)(qb + (size_t)n * NHEAD) = *(float4*)&qbv[0];
}

// ---------------- Count rows ----------------
__global__ __launch_bounds__(256) void count_kernel(
    const int* __restrict__ ei, int* __restrict__ counts)
{
    int e = blockIdx.x * 256 + threadIdx.x;
    if (e >= NE) return;
    atomicAdd(counts + ei[e], 1);
}

// ---------------- Hierarchical scan ----------------
__global__ __launch_bounds__(256) void scan_bsum_kernel(
    const int* __restrict__ counts, int* __restrict__ bsum)
{
    __shared__ int sd[256];
    int i = blockIdx.x * 256 + threadIdx.x;
    sd[threadIdx.x] = (i < NN) ? counts[i] : 0;
    __syncthreads();
    for (int s = 128; s > 0; s >>= 1) {
        if (threadIdx.x < (unsigned)s) sd[threadIdx.x] += sd[threadIdx.x + s];
        __syncthreads();
    }
    if (threadIdx.x == 0) bsum[blockIdx.x] = sd[0];
}

__global__ __launch_bounds__(256) void scan_top_kernel(int* __restrict__ bsum)
{
    __shared__ int tmp[256];
    int v = (threadIdx.x < NBLK) ? bsum[threadIdx.x] : 0;
    tmp[threadIdx.x] = v;
    __syncthreads();
    for (int d = 1; d < 256; d <<= 1) {
        int t = (threadIdx.x >= (unsigned)d) ? tmp[threadIdx.x - d] : 0;
        __syncthreads();
        tmp[threadIdx.x] += t;
        __syncthreads();
    }
    if (threadIdx.x < NBLK) bsum[threadIdx.x] = tmp[threadIdx.x] - v;  // exclusive
}

__global__ __launch_bounds__(256) void scan_final_kernel(
    const int* __restrict__ counts, const int* __restrict__ bsum,
    int* __restrict__ offsets, int* __restrict__ cursor)
{
    __shared__ int tmp[256];
    int i = blockIdx.x * 256 + threadIdx.x;
    int v = (i < NN) ? counts[i] : 0;
    tmp[threadIdx.x] = v;
    __syncthreads();
    for (int d = 1; d < 256; d <<= 1) {
        int t = (threadIdx.x >= (unsigned)d) ? tmp[threadIdx.x - d] : 0;
        __syncthreads();
        tmp[threadIdx.x] += t;
        __syncthreads();
    }
    int excl = tmp[threadIdx.x] - v + bsum[blockIdx.x];
    if (i < NN) { offsets[i] = excl; cursor[i] = excl; }
}

// ---------------- Kernel B: per-edge compute, CSR-direct payload write ----------------
__global__ __launch_bounds__(256) void edge_compute_kernel(
    const int* __restrict__ ei,
    const float* __restrict__ ea,
    const float* __restrict__ wkn_w1, const float* __restrict__ wkn_b1,
    const float* __restrict__ wkn_w2, const float* __restrict__ wkn_b2,
    const float* __restrict__ wvn_w1, const float* __restrict__ wvn_b1,
    const float* __restrict__ wvn_w2, const float* __restrict__ wvn_b2,
    const uint16_t* __restrict__ qt, const float* __restrict__ qb,
    const uint16_t* __restrict__ hk, const uint16_t* __restrict__ hv,
    int* __restrict__ cursor,
    uint16_t* __restrict__ payload, float* __restrict__ wfac)
{
    __shared__ float s_kn1[512], s_vn1[512];
    __shared__ float s_kn2[256], s_vn2[256];
    __shared__ float s_knb1[16], s_knb2[16], s_vnb1[16], s_vnb2[16];
    for (int i = threadIdx.x; i < 512; i += 256) { s_kn1[i] = wkn_w1[i]; s_vn1[i] = wvn_w1[i]; }
    if (threadIdx.x < 256) { s_kn2[threadIdx.x] = wkn_w2[threadIdx.x]; s_vn2[threadIdx.x] = wvn_w2[threadIdx.x]; }
    if (threadIdx.x < 16) {
        s_knb1[threadIdx.x] = wkn_b1[threadIdx.x]; s_knb2[threadIdx.x] = wkn_b2[threadIdx.x];
        s_vnb1[threadIdx.x] = wvn_b1[threadIdx.x]; s_vnb2[threadIdx.x] = wvn_b2[threadIdx.x];
    }
    __syncthreads();
    int e = blockIdx.x * 256 + threadIdx.x;
    if (e >= NE) return;

    int row = ei[e];
    int col = ei[NE + e];

    float eav[32];
    {
        const float4* p = (const float4*)(ea + (size_t)e * ECH);
        #pragma unroll
        for (int i = 0; i < 8; ++i) *(float4*)&eav[4 * i] = p[i];
    }

    float h1k[16], h1v[16];
    for (int o = 0; o < 16; ++o) {
        float sk = s_knb1[o], sv = s_vnb1[o];
        #pragma unroll
        for (int i = 0; i < 32; ++i) {
            sk += eav[i] * s_kn1[o * 32 + i];
            sv += eav[i] * s_vn1[o * 32 + i];
        }
        h1k[o] = ssp_f(sk);
        h1v[o] = ssp_f(sv);
    }
    float Wk[16], Wv[16];
    for (int o = 0; o < 16; ++o) {
        float sk = s_knb2[o], sv = s_vnb2[o];
        #pragma unroll
        for (int i = 0; i < 16; ++i) {
            sk += h1k[i] * s_kn2[o * 16 + i];
            sv += h1v[i] * s_vn2[o * 16 + i];
        }
        Wk[o] = sk; Wv[o] = sv;
    }

    int pos = atomicAdd(cursor + row, 1);

    float4 qbv = *(const float4*)(qb + (size_t)row * NHEAD);
    const float qbarr[4] = {qbv.x, qbv.y, qbv.z, qbv.w};
    const uint4* qtb = (const uint4*)(qt + (size_t)row * HD);
    const uint4* kb  = (const uint4*)(hk + (size_t)col * HD);
    const uint4* vb  = (const uint4*)(hv + (size_t)col * HD);
    uint4* pd = (uint4*)(payload + (size_t)pos * HD);
    float wf[NHEAD];

    #pragma unroll
    for (int h = 0; h < NHEAD; ++h) {
        float qr[16], kc[16], vc[16];
        unpack8(qtb[2 * h], qr); unpack8(qtb[2 * h + 1], qr + 8);
        unpack8(kb[2 * h], kc);  unpack8(kb[2 * h + 1], kc + 8);
        unpack8(vb[2 * h], vc);  unpack8(vb[2 * h + 1], vc + 8);
        float qk = qbarr[h];
        #pragma unroll
        for (int i = 0; i < 16; ++i) qk += qr[i] * Wk[i] * kc[i];
        float w = __expf(qk);   // softmax shift-invariance
        wf[h] = w;
        float o0[8], o1[8];
        #pragma unroll
        for (int i = 0; i < 8; ++i) o0[i] = w * Wv[i] * vc[i];
        #pragma unroll
        for (int i = 0; i < 8; ++i) o1[i] = w * Wv[8 + i] * vc[8 + i];
        pd[2 * h]     = pack8(o0);
        pd[2 * h + 1] = pack8(o1);
    }
    *(float4*)(wfac + (size_t)pos * NHEAD) = *(float4*)&wf[0];
}

// ---------------- Kernel E: streaming gather + normalize + wvl + cen + ssp + out ----------------
__global__ __launch_bounds__(256) void gather_finalize_kernel(
    const float* __restrict__ x,
    const uint16_t* __restrict__ payload, const float* __restrict__ wfac,
    const int* __restrict__ offsets, const int* __restrict__ counts,
    const float* __restrict__ wvl_w, const float* __restrict__ wvl_b,
    const float* __restrict__ cen_w, const float* __restrict__ cen_b,
    const float* __restrict__ out_w, const float* __restrict__ out_b,
    float* __restrict__ out)
{
    // cen/out weights TRANSPOSED in LDS: lane c reads s[i*64+c] -> 2-way alias = free
    __shared__ float s_cw[4096], s_ow[4096];
    __shared__ float s_wvl[256], s_vlb[16];
    __shared__ float s_m[4][64], s_x[4][64], s_t[4][64];
    for (int idx = threadIdx.x; idx < 4096; idx += 256) {
        int o = idx & 63, i = idx >> 6;
        s_cw[i * 64 + o] = cen_w[o * 64 + i];
        s_ow[i * 64 + o] = out_w[o * 64 + i];
    }
    if (threadIdx.x < 256) s_wvl[threadIdx.x] = wvl_w[threadIdx.x];
    if (threadIdx.x < 16) s_vlb[threadIdx.x] = wvl_b[threadIdx.x];
    __syncthreads();

    int l = threadIdx.x >> 6;   // wave id
    int L = threadIdx.x & 63;   // lane
    int q = L & 15, g = L >> 4; // channel-quad, edge-group
    int head4 = q >> 2;         // head owning channels 4q..4q+3

    for (int t = 0; t < 4; ++t) {
        int n = blockIdx.x * 16 + l * 4 + t;
        bool valid = n < NN;
        int st = 0, deg = 0;
        if (valid) { st = offsets[n]; deg = counts[n]; }
        float u0 = 0.f, u1 = 0.f, u2 = 0.f, u3 = 0.f, ds = 0.f;
        const uint16_t* pp = payload + (size_t)st * HD + 4 * q;
        const float* wp = wfac + (size_t)st * NHEAD + head4;
        int iters = (deg + 3) >> 2;
        for (int i = 0; i < iters; ++i) {
            int e = i * 4 + g;
            if (e < deg) {
                uint2 pv = *(const uint2*)(pp + (size_t)e * HD);  // 4 edges/wave-instr, 512B coalesced
                u0 += bf2f(pv.x & 0xffffu); u1 += bf2f(pv.x >> 16);
                u2 += bf2f(pv.y & 0xffffu); u3 += bf2f(pv.y >> 16);
                ds += wp[(size_t)e * NHEAD];
            }
        }
        // reduce over the 4 edge-groups (lanes differing in bits 4,5)
        u0 += __shfl_xor(u0, 16); u1 += __shfl_xor(u1, 16);
        u2 += __shfl_xor(u2, 16); u3 += __shfl_xor(u3, 16);
        ds += __shfl_xor(ds, 16);
        u0 += __shfl_xor(u0, 32); u1 += __shfl_xor(u1, 32);
        u2 += __shfl_xor(u2, 32); u3 += __shfl_xor(u3, 32);
        ds += __shfl_xor(ds, 32);

        float m0 = 0.f, m1 = 0.f, m2 = 0.f, m3 = 0.f;
        if (deg > 0) {
            float inv = 1.f / ds;
            m0 = u0 * inv; m1 = u1 * inv; m2 = u2 * inv; m3 = u3 * inv;
        }
        float msel = (g == 0) ? m0 : (g == 1) ? m1 : (g == 2) ? m2 : m3;
        s_m[l][4 * q + g] = msel;                 // all 64 channels covered uniquely
        s_x[l][L] = valid ? x[(size_t)n * HD + L] : 0.f;
        // s_m/s_x/s_t are same-wave private rows: no __syncthreads needed

        int c = L, h = c >> 4;
        float aggr = 0.f;
        if (deg > 0) {
            int o = c & 15;
            float s = s_vlb[o];
            #pragma unroll
            for (int i = 0; i < 16; ++i) s += s_m[l][h * 16 + i] * s_wvl[o * 16 + i];
            aggr = s;
        }
        float sc = cen_b[c];
        #pragma unroll 8
        for (int i = 0; i < 64; ++i) sc += s_x[l][i] * s_cw[i * 64 + c];
        sc += aggr;
        s_t[l][c] = ssp_f(sc);
        float so = out_b[c];
        #pragma unroll 8
        for (int i = 0; i < 64; ++i) so += s_t[l][i] * s_ow[i * 64 + c];
        if (valid) out[(size_t)n * HD + c] = so;
    }
}

extern "C" void kernel_launch(void* const* d_in, const int* in_sizes, int n_in,
                              void* d_out, int out_size, void* d_ws, size_t ws_size,
                              hipStream_t stream)
{
    const float* x      = (const float*)d_in[0];
    const int*   ei     = (const int*)d_in[1];
    const float* ea     = (const float*)d_in[2];
    const float* k_w    = (const float*)d_in[3];
    const float* q_w    = (const float*)d_in[4];
    const float* v_w    = (const float*)d_in[5];
    const float* wkn_w1 = (const float*)d_in[6];
    const float* wkn_b1 = (const float*)d_in[7];
    const float* wkn_w2 = (const float*)d_in[8];
    const float* wkn_b2 = (const float*)d_in[9];
    const float* wkl_w  = (const float*)d_in[10];
    const float* wkl_b  = (const float*)d_in[11];
    const float* wvn_w1 = (const float*)d_in[12];
    const float* wvn_b1 = (const float*)d_in[13];
    const float* wvn_w2 = (const float*)d_in[14];
    const float* wvn_b2 = (const float*)d_in[15];
    const float* wvl_w  = (const float*)d_in[16];
    const float* wvl_b  = (const float*)d_in[17];
    const float* cen_w  = (const float*)d_in[18];
    const float* cen_b  = (const float*)d_in[19];
    const float* out_w  = (const float*)d_in[20];
    const float* out_b  = (const float*)d_in[21];
    float* out = (float*)d_out;

    // workspace layout
    float* qb    = (float*)d_ws;                              // NN*4 f32
    float* wfac  = qb + (size_t)NN * NHEAD;                   // NE*4 f32
    uint16_t* qt = (uint16_t*)(wfac + (size_t)NE * NHEAD);    // NN*64 bf16
    uint16_t* hk = qt + (size_t)NN * HD;                      // NN*64 bf16
    uint16_t* hv = hk + (size_t)NN * HD;                      // NN*64 bf16
    uint16_t* payload = hv + (size_t)NN * HD;                 // NE*64 bf16
    int* counts  = (int*)(payload + (size_t)NE * HD);         // NN
    int* bsum    = counts + NN;                               // 256
    int* offsets = bsum + 256;                                // NN
    int* cursor  = offsets + NN;                              // NN

    hipMemsetAsync(counts, 0, (size_t)NN * sizeof(int), stream);
    node_transform_kernel<<<NBLK, 256, 0, stream>>>(
        x, k_w, q_w, v_w, wkl_w, wkl_b, qt, qb, hk, hv);
    count_kernel<<<(NE + 255) / 256, 256, 0, stream>>>(ei, counts);
    scan_bsum_kernel<<<NBLK, 256, 0, stream>>>(counts, bsum);
    scan_top_kernel<<<1, 256, 0, stream>>>(bsum);
    scan_final_kernel<<<NBLK, 256, 0, stream>>>(counts, bsum, offsets, cursor);
    edge_compute_kernel<<<(NE + 255) / 256, 256, 0, stream>>>(
        ei, ea, wkn_w1, wkn_b1, wkn_w2, wkn_b2,
        wvn_w1, wvn_b1, wvn_w2, wvn_b2,
        qt, qb, hk, hv, cursor, payload, wfac);
    gather_finalize_kernel<<<(NN + 15) / 16, 256, 0, stream>>>(
        x, payload, wfac, offsets, counts,
        wvl_w, wvl_b, cen_w, cen_b, out_w, out_b, out);
}